// Round 2
// baseline (748.167 us; speedup 1.0000x reference)
//
#include <hip/hip_runtime.h>
#include <stdint.h>

typedef __attribute__((ext_vector_type(8))) short s16x8;
typedef __attribute__((ext_vector_type(4))) float f32x4;

__device__ __forceinline__ short f2bf(float f){
  union { float f; uint32_t u; } v; v.f = f;
  uint32_t u = v.u;
  u += 0x7fffu + ((u >> 16) & 1u);
  return (short)(u >> 16);
}
__device__ __forceinline__ float bf2f(short s){
  union { uint32_t u; float f; } v; v.u = ((uint32_t)(uint16_t)s) << 16;
  return v.f;
}
__device__ __forceinline__ float sigm(float x){
  return __fdividef(1.f, 1.f + __expf(-x));
}
__device__ __forceinline__ float tanh_fast(float x){
  return 1.f - __fdividef(2.f, __expf(2.f * x) + 1.f);
}

#define MFMA16(a, b, c) __builtin_amdgcn_mfma_f32_16x16x32_bf16((a), (b), (c), 0, 0, 0)

// Fused TemporalEncoder: conv1(1->16,k3,causal)+ReLU -> conv2(16->32,k3,causal)+ReLU
// -> GRU(32->64) over T=100, emit final hidden state.
// Block = 256 threads (4 waves) owns M=8 sequences (rows 8..15 of the 16-row
// MFMA tiles are dead but finite). grid=1024 -> 4 blocks/CU -> 4 waves/SIMD
// for latency hiding of the serial per-step chain.
// Wave w owns hidden dims [16w,16w+16) and gate tiles {w, w+4, w+8}.
__global__ __launch_bounds__(256, 4) void te_fused(
    const float* __restrict__ x,
    const float* __restrict__ w1, const float* __restrict__ b1,
    const float* __restrict__ w2, const float* __restrict__ b2,
    const float* __restrict__ Wih, const float* __restrict__ Whh,
    const float* __restrict__ bih, const float* __restrict__ bhh,
    float* __restrict__ out)
{
  constexpr int T = 100;
  constexpr int M = 8;                   // live sequences per block
  __shared__ float x_s[M * T];           // staged input rows (live rows only)
  __shared__ short hA[2][2][16 * 72];    // [buf][hi/lo][seq16][72-padded k] bf16 h
  __shared__ short ring[4][16 * 24];     // c1 ring: [slot=t%4][seq16][24-padded ch(16)]
  __shared__ short s_s[2][16 * 40];      // conv2 out s_t: [buf][seq16][40-padded ch(32)]

  const int tid  = threadIdx.x;
  const int lane = tid & 63;
  const int wv   = tid >> 6;    // wave 0..3
  const int l15  = lane & 15;
  const int lg   = lane >> 4;   // 0..3
  const int seq0 = blockIdx.x * M;
  const int sl   = tid >> 4;    // conv1: seq row 0..15 (only <M live)
  const int chc  = tid & 15;    // conv1: channel 0..15

  // ---- stage x (M*100 floats per block, 16B aligned) ----
  {
    const float4* gx = reinterpret_cast<const float4*>(x + (size_t)seq0 * T);
    float4* sx = reinterpret_cast<float4*>(x_s);
    for (int i = tid; i < (M * T) / 4; i += 256) sx[i] = gx[i];
  }
  // zero h buffer 0 (hi+lo) and the whole c1 ring (stale/dead rows stay 0)
  {
    int* p = reinterpret_cast<int*>(&hA[0][0][0]);
    for (int i = tid; i < (2 * 16 * 72) / 2; i += 256) p[i] = 0;
    int* q = reinterpret_cast<int*>(&ring[0][0]);
    for (int i = tid; i < (4 * 16 * 24) / 2; i += 256) q[i] = 0;
  }

  // ---- build weight B-fragments in registers ----
  // B[k][n] layout: lane holds n = l&15 (+tile base), k = (l>>4)*8 + j
  s16x8 WhhHi[3][2], WhhLo[3][2], WihHi[3], WihLo[3];
  float bihv[3], bhhv[3];
#pragma unroll
  for (int g = 0; g < 3; ++g) {
    const int n = 64 * g + 16 * wv + l15;      // global gate row
    bihv[g] = bih[n];
    bhhv[g] = bhh[n];
#pragma unroll
    for (int ks = 0; ks < 2; ++ks) {
      const float* p = Whh + n * 64 + ks * 32 + lg * 8;
#pragma unroll
      for (int j = 0; j < 8; ++j) {
        float f = p[j];
        short hi = f2bf(f);
        WhhHi[g][ks][j] = hi;
        WhhLo[g][ks][j] = f2bf(f - bf2f(hi));
      }
    }
    const float* q = Wih + n * 32 + lg * 8;
#pragma unroll
    for (int j = 0; j < 8; ++j) {
      float f = q[j];
      short hi = f2bf(f);
      WihHi[g][j] = hi;
      WihLo[g][j] = f2bf(f - bf2f(hi));
    }
  }

  // conv2 B-fragments per ring phase (used by waves 0,1; ntile = wv&1)
  // d = (slot-ph)&3 : d==0 -> tap 2, d==3 -> tap 1, d==2 -> tap 0, d==1 -> B=0
  s16x8 cW[4][2];
  float b2v;
  {
    const int nt = wv & 1;
    const int ch = 16 * nt + l15;
    b2v = b2[ch];
#pragma unroll
    for (int ph = 0; ph < 4; ++ph)
#pragma unroll
      for (int ks = 0; ks < 2; ++ks) {
        s16x8 h8;
#pragma unroll
        for (int j = 0; j < 8; ++j) {
          const int k = ks * 32 + lg * 8 + j;
          const int st = k >> 4, ii = k & 15;
          const int d = (st - ph) & 3;
          float f = 0.f;
          if (d != 1) {
            const int a = (d == 0) ? 2 : ((d == 3) ? 1 : 0);
            f = w2[ch * 48 + ii * 3 + a];
          }
          h8[j] = f2bf(f);
        }
        cW[ph][ks] = h8;
      }
  }

  // conv1 per-thread weights
  const float w1v0 = w1[chc * 3 + 0], w1v1 = w1[chc * 3 + 1], w1v2 = w1[chc * 3 + 2];
  const float b1v = b1[chc];

  __syncthreads();

  const bool c1on = (sl < M);
  float xa_r = c1on ? x_s[sl * T + 0] : 0.f;
  float xb_r = c1on ? x_s[sl * T + 1] : 0.f;

  // conv2 A-frag addressing: k-group k0 = ks*32 + lg*8 -> slot k0>>4, offset (k0&15)
  const int i0a = (lg & 1) * 8;
  const int sA0 = lg >> 1;
  const int sA1 = 2 + (lg >> 1);

  auto conv2_step = [&](int ph, int buf) {
    s16x8 a0 = *reinterpret_cast<const s16x8*>(&ring[sA0][l15 * 24 + i0a]);
    s16x8 a1 = *reinterpret_cast<const s16x8*>(&ring[sA1][l15 * 24 + i0a]);
    s16x8 cb0, cb1;
    switch (ph) {   // static frag indices (avoid scratch spill)
      case 0: cb0 = cW[0][0]; cb1 = cW[0][1]; break;
      case 1: cb0 = cW[1][0]; cb1 = cW[1][1]; break;
      case 2: cb0 = cW[2][0]; cb1 = cW[2][1]; break;
      default: cb0 = cW[3][0]; cb1 = cW[3][1]; break;
    }
    f32x4 sa = { b2v, b2v, b2v, b2v };
    sa = MFMA16(a0, cb0, sa);
    sa = MFMA16(a1, cb1, sa);
    short* sw = &s_s[buf][0];
#pragma unroll
    for (int i2 = 0; i2 < 4; ++i2) {
      float v = sa[i2];
      v = v > 0.f ? v : 0.f;
      sw[(lg * 4 + i2) * 40 + (wv & 1) * 16 + l15] = f2bf(v);
    }
  };

  // ---- prologue: c1(0) -> s(0) -> c1(1) ----
  if (c1on) {
    float c = b1v + w1v2 * xa_r;              // c1(0): taps x(-2)=x(-1)=0
    c = c > 0.f ? c : 0.f;
    ring[0][sl * 24 + chc] = f2bf(c);
  }
  __syncthreads();
  if (wv < 2) conv2_step(0, 0);               // s(0); slots 1..3 are zero
  if (c1on) {
    float c = b1v + w1v1 * xa_r + w1v2 * xb_r; // c1(1)
    c = c > 0.f ? c : 0.f;
    ring[1][sl * 24 + chc] = f2bf(c);
  }
  __syncthreads();

  float hreg[4] = {0.f, 0.f, 0.f, 0.f};

  for (int t = 0; t < T; ++t) {
    // A-fragments: s(t) and h(t-1) hi/lo
    s16x8 as_ = *reinterpret_cast<const s16x8*>(&s_s[t & 1][l15 * 40 + lg * 8]);
    const short* hb = &hA[t & 1][0][0];
    const short* lb = &hA[t & 1][1][0];
    const int ho = l15 * 72 + lg * 8;
    s16x8 ah0 = *reinterpret_cast<const s16x8*>(hb + ho);
    s16x8 ah1 = *reinterpret_cast<const s16x8*>(hb + ho + 32);
    s16x8 al0 = *reinterpret_cast<const s16x8*>(lb + ho);
    s16x8 al1 = *reinterpret_cast<const s16x8*>(lb + ho + 32);

    f32x4 xpa[3], gha[3];
#pragma unroll
    for (int g = 0; g < 3; ++g) {
      f32x4 xa4 = { bihv[g], bihv[g], bihv[g], bihv[g] };
      xa4 = MFMA16(as_, WihHi[g], xa4);        // xp = s @ Wih^T (split-2 on W)
      xa4 = MFMA16(as_, WihLo[g], xa4);
      xpa[g] = xa4;
      // two independent 3-deep chains instead of one 6-deep chain
      f32x4 ga = { bhhv[g], bhhv[g], bhhv[g], bhhv[g] };
      ga = MFMA16(ah0, WhhHi[g][0], ga);
      ga = MFMA16(ah1, WhhHi[g][1], ga);
      ga = MFMA16(al0, WhhHi[g][0], ga);
      f32x4 gb = { 0.f, 0.f, 0.f, 0.f };
      gb = MFMA16(al1, WhhHi[g][1], gb);
      gb = MFMA16(ah0, WhhLo[g][0], gb);
      gb = MFMA16(ah1, WhhLo[g][1], gb);
      gha[g] = ga + gb;
    }

    // pipeline: produce s(t+1) and c1(t+2) for later steps
    if (t < T - 1 && wv < 2) conv2_step((t + 1) & 3, (t + 1) & 1);

    if (t < T - 2 && c1on) {
      float xc = x_s[sl * T + t + 2];
      float c = b1v + w1v0 * xa_r + w1v1 * xb_r + w1v2 * xc;  // c1(t+2)
      c = c > 0.f ? c : 0.f;
      ring[(t + 2) & 3][sl * 24 + chc] = f2bf(c);
      xa_r = xb_r; xb_r = xc;
    }

    // GRU elementwise; D layout: seq = lg*4+i2, hidden dim j = 16*wv + l15
    short* hwh = &hA[(t + 1) & 1][0][0];
    short* hwl = &hA[(t + 1) & 1][1][0];
#pragma unroll
    for (int i2 = 0; i2 < 4; ++i2) {
      float r = sigm(xpa[0][i2] + gha[0][i2]);
      float z = sigm(xpa[1][i2] + gha[1][i2]);
      float nn = tanh_fast(xpa[2][i2] + r * gha[2][i2]);
      float h = (1.f - z) * nn + z * hreg[i2];
      hreg[i2] = h;
      short hi = f2bf(h);
      short lo = f2bf(h - bf2f(hi));
      const int idx = (lg * 4 + i2) * 72 + 16 * wv + l15;
      hwh[idx] = hi;
      hwl[idx] = lo;
    }
    __syncthreads();
  }

  if (lg < 2) {     // only live sequence rows (seq = lg*4+i2 < 8)
#pragma unroll
    for (int i2 = 0; i2 < 4; ++i2) {
      out[(size_t)(seq0 + lg * 4 + i2) * 64 + 16 * wv + l15] = hreg[i2];
    }
  }
}

extern "C" void kernel_launch(void* const* d_in, const int* in_sizes, int n_in,
                              void* d_out, int out_size, void* d_ws, size_t ws_size,
                              hipStream_t stream)
{
  (void)in_sizes; (void)n_in; (void)d_ws; (void)ws_size; (void)out_size;
  const float* x   = (const float*)d_in[0];
  const float* w1  = (const float*)d_in[1];
  const float* b1  = (const float*)d_in[2];
  const float* w2  = (const float*)d_in[3];
  const float* b2  = (const float*)d_in[4];
  const float* Wih = (const float*)d_in[5];
  const float* Whh = (const float*)d_in[6];
  const float* bih = (const float*)d_in[7];
  const float* bhh = (const float*)d_in[8];
  float* out = (float*)d_out;
  te_fused<<<1024, 256, 0, stream>>>(x, w1, b1, w2, b2, Wih, Whh, bih, bhh, out);
}

// Round 3
// 305.215 us; speedup vs baseline: 2.4513x; 2.4513x over previous
//
#include <hip/hip_runtime.h>
#include <stdint.h>

typedef __attribute__((ext_vector_type(8))) short s16x8;
typedef __attribute__((ext_vector_type(4))) float f32x4;

__device__ __forceinline__ short f2bf(float f){
  union { float f; uint32_t u; } v; v.f = f;
  uint32_t u = v.u;
  u += 0x7fffu + ((u >> 16) & 1u);
  return (short)(u >> 16);
}
__device__ __forceinline__ float bf2f(short s){
  union { uint32_t u; float f; } v; v.u = ((uint32_t)(uint16_t)s) << 16;
  return v.f;
}
__device__ __forceinline__ float sigm(float x){
  return __fdividef(1.f, 1.f + __expf(-x));
}
__device__ __forceinline__ float tanh_fast(float x){
  return 1.f - __fdividef(2.f, __expf(2.f * x) + 1.f);
}

#define MFMA16(a, b, c) __builtin_amdgcn_mfma_f32_16x16x32_bf16((a), (b), (c), 0, 0, 0)

// Fused TemporalEncoder: conv1(1->16,k3,causal)+ReLU -> conv2(16->32,k3,causal)+ReLU
// -> GRU(32->64) over T=100, emit final hidden state.
// Block = 256 threads (4 waves) owns M=8 sequences (rows 8..15 of the 16-row
// MFMA tiles are dead but finite). grid=1024 -> 4 blocks/CU.
// NOTE: __launch_bounds__(256,2), NOT (256,4): the min-waves=4 variant caps the
// unified VGPR+AGPR file at 128 -> arch VGPRs 64 -> weight frags spill to
// scratch -> 2.3 GB/dispatch HBM read traffic (round-2 post-mortem). At
// VGPR=120 the HW fits 4 waves/SIMD natively (4*120=480<=512) without the cap.
// Wave w owns hidden dims [16w,16w+16) and gate tiles {w, w+4, w+8}.
__global__ __launch_bounds__(256, 2) void te_fused(
    const float* __restrict__ x,
    const float* __restrict__ w1, const float* __restrict__ b1,
    const float* __restrict__ w2, const float* __restrict__ b2,
    const float* __restrict__ Wih, const float* __restrict__ Whh,
    const float* __restrict__ bih, const float* __restrict__ bhh,
    float* __restrict__ out)
{
  constexpr int T = 100;
  constexpr int M = 8;                   // live sequences per block
  __shared__ float x_s[M * T];           // staged input rows (live rows only)
  __shared__ short hA[2][2][16 * 72];    // [buf][hi/lo][seq16][72-padded k] bf16 h
  __shared__ short ring[4][16 * 24];     // c1 ring: [slot=t%4][seq16][24-padded ch(16)]
  __shared__ short s_s[2][16 * 40];      // conv2 out s_t: [buf][seq16][40-padded ch(32)]

  const int tid  = threadIdx.x;
  const int lane = tid & 63;
  const int wv   = tid >> 6;    // wave 0..3
  const int l15  = lane & 15;
  const int lg   = lane >> 4;   // 0..3
  const int seq0 = blockIdx.x * M;
  const int sl   = tid >> 4;    // conv1: seq row 0..15 (only <M live)
  const int chc  = tid & 15;    // conv1: channel 0..15

  // ---- stage x (M*100 floats per block, 16B aligned) ----
  {
    const float4* gx = reinterpret_cast<const float4*>(x + (size_t)seq0 * T);
    float4* sx = reinterpret_cast<float4*>(x_s);
    for (int i = tid; i < (M * T) / 4; i += 256) sx[i] = gx[i];
  }
  // zero h buffer 0 (hi+lo) and the whole c1 ring (stale/dead rows stay 0)
  {
    int* p = reinterpret_cast<int*>(&hA[0][0][0]);
    for (int i = tid; i < (2 * 16 * 72) / 2; i += 256) p[i] = 0;
    int* q = reinterpret_cast<int*>(&ring[0][0]);
    for (int i = tid; i < (4 * 16 * 24) / 2; i += 256) q[i] = 0;
  }

  // ---- build weight B-fragments in registers ----
  // B[k][n] layout: lane holds n = l&15 (+tile base), k = (l>>4)*8 + j
  s16x8 WhhHi[3][2], WhhLo[3][2], WihHi[3], WihLo[3];
  float bihv[3], bhhv[3];
#pragma unroll
  for (int g = 0; g < 3; ++g) {
    const int n = 64 * g + 16 * wv + l15;      // global gate row
    bihv[g] = bih[n];
    bhhv[g] = bhh[n];
#pragma unroll
    for (int ks = 0; ks < 2; ++ks) {
      const float* p = Whh + n * 64 + ks * 32 + lg * 8;
#pragma unroll
      for (int j = 0; j < 8; ++j) {
        float f = p[j];
        short hi = f2bf(f);
        WhhHi[g][ks][j] = hi;
        WhhLo[g][ks][j] = f2bf(f - bf2f(hi));
      }
    }
    const float* q = Wih + n * 32 + lg * 8;
#pragma unroll
    for (int j = 0; j < 8; ++j) {
      float f = q[j];
      short hi = f2bf(f);
      WihHi[g][j] = hi;
      WihLo[g][j] = f2bf(f - bf2f(hi));
    }
  }

  // conv2 B-fragments per ring phase (used by waves 0,1; ntile = wv&1)
  // d = (slot-ph)&3 : d==0 -> tap 2, d==3 -> tap 1, d==2 -> tap 0, d==1 -> B=0
  s16x8 cW[4][2];
  float b2v;
  {
    const int nt = wv & 1;
    const int ch = 16 * nt + l15;
    b2v = b2[ch];
#pragma unroll
    for (int ph = 0; ph < 4; ++ph)
#pragma unroll
      for (int ks = 0; ks < 2; ++ks) {
        s16x8 h8;
#pragma unroll
        for (int j = 0; j < 8; ++j) {
          const int k = ks * 32 + lg * 8 + j;
          const int st = k >> 4, ii = k & 15;
          const int d = (st - ph) & 3;
          float f = 0.f;
          if (d != 1) {
            const int a = (d == 0) ? 2 : ((d == 3) ? 1 : 0);
            f = w2[ch * 48 + ii * 3 + a];
          }
          h8[j] = f2bf(f);
        }
        cW[ph][ks] = h8;
      }
  }

  // conv1 per-thread weights
  const float w1v0 = w1[chc * 3 + 0], w1v1 = w1[chc * 3 + 1], w1v2 = w1[chc * 3 + 2];
  const float b1v = b1[chc];

  __syncthreads();

  const bool c1on = (sl < M);
  float xa_r = c1on ? x_s[sl * T + 0] : 0.f;
  float xb_r = c1on ? x_s[sl * T + 1] : 0.f;

  // conv2 A-frag addressing: k-group k0 = ks*32 + lg*8 -> slot k0>>4, offset (k0&15)
  const int i0a = (lg & 1) * 8;
  const int sA0 = lg >> 1;
  const int sA1 = 2 + (lg >> 1);

  auto conv2_step = [&](int ph, int buf) {
    s16x8 a0 = *reinterpret_cast<const s16x8*>(&ring[sA0][l15 * 24 + i0a]);
    s16x8 a1 = *reinterpret_cast<const s16x8*>(&ring[sA1][l15 * 24 + i0a]);
    s16x8 cb0, cb1;
    switch (ph) {   // static frag indices (avoid scratch spill)
      case 0: cb0 = cW[0][0]; cb1 = cW[0][1]; break;
      case 1: cb0 = cW[1][0]; cb1 = cW[1][1]; break;
      case 2: cb0 = cW[2][0]; cb1 = cW[2][1]; break;
      default: cb0 = cW[3][0]; cb1 = cW[3][1]; break;
    }
    f32x4 sa = { b2v, b2v, b2v, b2v };
    sa = MFMA16(a0, cb0, sa);
    sa = MFMA16(a1, cb1, sa);
    short* sw = &s_s[buf][0];
#pragma unroll
    for (int i2 = 0; i2 < 4; ++i2) {
      float v = sa[i2];
      v = v > 0.f ? v : 0.f;
      sw[(lg * 4 + i2) * 40 + (wv & 1) * 16 + l15] = f2bf(v);
    }
  };

  // ---- prologue: c1(0) -> s(0) -> c1(1) ----
  if (c1on) {
    float c = b1v + w1v2 * xa_r;              // c1(0): taps x(-2)=x(-1)=0
    c = c > 0.f ? c : 0.f;
    ring[0][sl * 24 + chc] = f2bf(c);
  }
  __syncthreads();
  if (wv < 2) conv2_step(0, 0);               // s(0); slots 1..3 are zero
  if (c1on) {
    float c = b1v + w1v1 * xa_r + w1v2 * xb_r; // c1(1)
    c = c > 0.f ? c : 0.f;
    ring[1][sl * 24 + chc] = f2bf(c);
  }
  __syncthreads();

  float hreg[4] = {0.f, 0.f, 0.f, 0.f};

  for (int t = 0; t < T; ++t) {
    // A-fragments: s(t) and h(t-1) hi/lo
    s16x8 as_ = *reinterpret_cast<const s16x8*>(&s_s[t & 1][l15 * 40 + lg * 8]);
    const short* hb = &hA[t & 1][0][0];
    const short* lb = &hA[t & 1][1][0];
    const int ho = l15 * 72 + lg * 8;
    s16x8 ah0 = *reinterpret_cast<const s16x8*>(hb + ho);
    s16x8 ah1 = *reinterpret_cast<const s16x8*>(hb + ho + 32);
    s16x8 al0 = *reinterpret_cast<const s16x8*>(lb + ho);
    s16x8 al1 = *reinterpret_cast<const s16x8*>(lb + ho + 32);

    f32x4 xpa[3], gha[3];
#pragma unroll
    for (int g = 0; g < 3; ++g) {
      f32x4 xa4 = { bihv[g], bihv[g], bihv[g], bihv[g] };
      xa4 = MFMA16(as_, WihHi[g], xa4);        // xp = s @ Wih^T (split-2 on W)
      xa4 = MFMA16(as_, WihLo[g], xa4);
      xpa[g] = xa4;
      // two independent 3-deep chains instead of one 6-deep chain
      f32x4 ga = { bhhv[g], bhhv[g], bhhv[g], bhhv[g] };
      ga = MFMA16(ah0, WhhHi[g][0], ga);
      ga = MFMA16(ah1, WhhHi[g][1], ga);
      ga = MFMA16(al0, WhhHi[g][0], ga);
      f32x4 gb = { 0.f, 0.f, 0.f, 0.f };
      gb = MFMA16(al1, WhhHi[g][1], gb);
      gb = MFMA16(ah0, WhhLo[g][0], gb);
      gb = MFMA16(ah1, WhhLo[g][1], gb);
      gha[g] = ga + gb;
    }

    // pipeline: produce s(t+1) and c1(t+2) for later steps
    if (t < T - 1 && wv < 2) conv2_step((t + 1) & 3, (t + 1) & 1);

    if (t < T - 2 && c1on) {
      float xc = x_s[sl * T + t + 2];
      float c = b1v + w1v0 * xa_r + w1v1 * xb_r + w1v2 * xc;  // c1(t+2)
      c = c > 0.f ? c : 0.f;
      ring[(t + 2) & 3][sl * 24 + chc] = f2bf(c);
      xa_r = xb_r; xb_r = xc;
    }

    // GRU elementwise; D layout: seq = lg*4+i2, hidden dim j = 16*wv + l15
    short* hwh = &hA[(t + 1) & 1][0][0];
    short* hwl = &hA[(t + 1) & 1][1][0];
#pragma unroll
    for (int i2 = 0; i2 < 4; ++i2) {
      float r = sigm(xpa[0][i2] + gha[0][i2]);
      float z = sigm(xpa[1][i2] + gha[1][i2]);
      float nn = tanh_fast(xpa[2][i2] + r * gha[2][i2]);
      float h = (1.f - z) * nn + z * hreg[i2];
      hreg[i2] = h;
      short hi = f2bf(h);
      short lo = f2bf(h - bf2f(hi));
      const int idx = (lg * 4 + i2) * 72 + 16 * wv + l15;
      hwh[idx] = hi;
      hwl[idx] = lo;
    }
    __syncthreads();
  }

  if (lg < 2) {     // only live sequence rows (seq = lg*4+i2 < 8)
#pragma unroll
    for (int i2 = 0; i2 < 4; ++i2) {
      out[(size_t)(seq0 + lg * 4 + i2) * 64 + 16 * wv + l15] = hreg[i2];
    }
  }
}

extern "C" void kernel_launch(void* const* d_in, const int* in_sizes, int n_in,
                              void* d_out, int out_size, void* d_ws, size_t ws_size,
                              hipStream_t stream)
{
  (void)in_sizes; (void)n_in; (void)d_ws; (void)ws_size; (void)out_size;
  const float* x   = (const float*)d_in[0];
  const float* w1  = (const float*)d_in[1];
  const float* b1  = (const float*)d_in[2];
  const float* w2  = (const float*)d_in[3];
  const float* b2  = (const float*)d_in[4];
  const float* Wih = (const float*)d_in[5];
  const float* Whh = (const float*)d_in[6];
  const float* bih = (const float*)d_in[7];
  const float* bhh = (const float*)d_in[8];
  float* out = (float*)d_out;
  te_fused<<<1024, 256, 0, stream>>>(x, w1, b1, w2, b2, Wih, Whh, bih, bhh, out);
}

// Round 4
// 88.699 us; speedup vs baseline: 8.4349x; 3.4410x over previous
//
#include <hip/hip_runtime.h>
#include <stdint.h>

typedef __attribute__((ext_vector_type(8))) short s16x8;
typedef __attribute__((ext_vector_type(4))) float f32x4;

__device__ __forceinline__ short f2bf(float f){
  union { float f; uint32_t u; } v; v.f = f;
  uint32_t u = v.u;
  u += 0x7fffu + ((u >> 16) & 1u);
  return (short)(u >> 16);
}
__device__ __forceinline__ float sigm_fast(float x){
  // 1/(1+exp(-x)) = rcp(1 + exp2(-x*log2e))   [mul, exp, add, rcp]
  float e = __builtin_amdgcn_exp2f(x * -1.44269504f);
  return __builtin_amdgcn_rcpf(1.f + e);
}
__device__ __forceinline__ float tanh_fast(float x){
  // 1 - 2/(exp(2x)+1) = fma(-2, rcp(exp2(x*2*log2e)+1), 1)
  float e = __builtin_amdgcn_exp2f(x * 2.88539008f);
  return __builtin_fmaf(-2.f, __builtin_amdgcn_rcpf(e + 1.f), 1.f);
}

#define MFMA16(a, b, c) __builtin_amdgcn_mfma_f32_16x16x32_bf16((a), (b), (c), 0, 0, 0)

// Fused TemporalEncoder: conv1(1->16,k3,causal)+ReLU -> conv2(16->32,k3,causal)+ReLU
// -> GRU(32->64) over T=100, emit final hidden state.
// Block = 256 threads (4 waves) owns M=16 sequences; grid = 512 (2 blocks/CU).
// Round-3 lesson: residency is reg-capped at 2 blocks/CU regardless of grid, and
// time scales with issued work -> minimize per-step issue, keep M=16 full tiles.
// Numerics: h single bf16 (fp32 carried in regs), Whh split-2 bf16, Wih hi only.
// r/z gates: single 5-deep MFMA chain (bias as hoisted C-input, no VALU adds).
__global__ __launch_bounds__(256, 2) void te_fused(
    const float* __restrict__ x,
    const float* __restrict__ w1, const float* __restrict__ b1,
    const float* __restrict__ w2, const float* __restrict__ b2,
    const float* __restrict__ Wih, const float* __restrict__ Whh,
    const float* __restrict__ bih, const float* __restrict__ bhh,
    float* __restrict__ out)
{
  constexpr int T = 100;
  constexpr int M = 16;                  // sequences per block (full MFMA tiles)
  __shared__ float x_s[M * T];           // staged input rows
  __shared__ short hA[2][16 * 72];       // [buf][seq][72-padded dim] bf16 h
  __shared__ short ring[4][16 * 24];     // c1 ring: [slot=tau%4][seq][24-padded ch(16)]
  __shared__ short s_s[2][16 * 40];      // conv2 out s_t: [buf][seq][40-padded ch(32)]

  const int tid  = threadIdx.x;
  const int lane = tid & 63;
  const int wv   = tid >> 6;    // wave 0..3
  const int l15  = lane & 15;
  const int lg   = lane >> 4;   // 0..3
  const int seq0 = blockIdx.x * M;
  const int sl   = tid >> 4;    // conv1: seq row 0..15
  const int chc  = tid & 15;    // conv1: channel 0..15

  // ---- stage x (16*100 floats per block, 16B aligned) ----
  {
    const float4* gx = reinterpret_cast<const float4*>(x + (size_t)seq0 * T);
    float4* sx = reinterpret_cast<float4*>(x_s);
    for (int i = tid; i < (M * T) / 4; i += 256) sx[i] = gx[i];
  }
  // zero h buffer 0 and the whole c1 ring (prologue + stale slots must be 0/finite)
  {
    int* p = reinterpret_cast<int*>(&hA[0][0]);
    for (int i = tid; i < (16 * 72) / 2; i += 256) p[i] = 0;
    int* q = reinterpret_cast<int*>(&ring[0][0]);
    for (int i = tid; i < (4 * 16 * 24) / 2; i += 256) q[i] = 0;
  }

  // ---- weight B-fragments in registers ----
  // B[k][n]: lane holds n = l15 (+tile base), k = lg*8 + j (+32*ks)
  s16x8 WhhHi[3][2], WhhLo[3][2], WihHi[3];
  f32x4 bias_r, bias_z, bias_xn, bias_hn;
#pragma unroll
  for (int g = 0; g < 3; ++g) {
    const int n = 64 * g + 16 * wv + l15;      // global gate row
#pragma unroll
    for (int ks = 0; ks < 2; ++ks) {
      const float* p = Whh + n * 64 + ks * 32 + lg * 8;
#pragma unroll
      for (int j = 0; j < 8; ++j) {
        float f = p[j];
        short hi = f2bf(f);
        WhhHi[g][ks][j] = hi;
        union { uint32_t u; float ff; } vv; vv.u = ((uint32_t)(uint16_t)hi) << 16;
        WhhLo[g][ks][j] = f2bf(f - vv.ff);
      }
    }
    const float* q = Wih + n * 32 + lg * 8;
#pragma unroll
    for (int j = 0; j < 8; ++j) WihHi[g][j] = f2bf(q[j]);
    float bi = bih[n], bh = bhh[n];
    if (g == 0) { float v = bi + bh; bias_r  = (f32x4){v, v, v, v}; }
    if (g == 1) { float v = bi + bh; bias_z  = (f32x4){v, v, v, v}; }
    if (g == 2) { bias_xn = (f32x4){bi, bi, bi, bi};
                  bias_hn = (f32x4){bh, bh, bh, bh}; }
  }

  // conv2 B-fragments, FIXED tap mapping (slot rotation moved to A addresses):
  // flat k = ks*32 + lg*8 + j; group g = k>>4 (0..3); g<3 -> tap g, g==3 -> 0.
  s16x8 cW2[2];
  f32x4 b2v4;
  {
    const int nt = wv & 1;
    const int ch = 16 * nt + l15;
    float bv = b2[ch];
    b2v4 = (f32x4){bv, bv, bv, bv};
#pragma unroll
    for (int ks = 0; ks < 2; ++ks) {
      s16x8 h8;
#pragma unroll
      for (int j = 0; j < 8; ++j) {
        const int k = ks * 32 + lg * 8 + j;
        const int g = k >> 4, ii = k & 15;
        h8[j] = (g < 3) ? f2bf(w2[ch * 48 + ii * 3 + g]) : (short)0;
      }
      cW2[ks] = h8;
    }
  }

  // conv1 per-thread weights
  const float w1v0 = w1[chc * 3 + 0], w1v1 = w1[chc * 3 + 1], w1v2 = w1[chc * 3 + 2];
  const float b1v = b1[chc];

  __syncthreads();

  float xa_r = x_s[sl * T + 0];
  float xb_r = x_s[sl * T + 1];

  // conv2 A addressing: frag0 covers k-groups {0,1} (tap u-2+g), frag1 groups {2,3}.
  // group within frag = lg>>1; in-group offset = (lg&1)*8.
  // slot(tap g) = (u-2+g) & 3. Group 3 is multiplied by B=0 (reads garbage-but-
  // finite slot; ring only ever holds ReLU'd bf16 or 0 -> no NaN).
  const int i0a = (lg & 1) * 8;
  const int grp = lg >> 1;

  auto conv2_step = [&](int u, int buf) {
    const int sA0 = (u + 2 + grp) & 3;
    const int sA1 = (u + grp) & 3;
    s16x8 a0 = *reinterpret_cast<const s16x8*>(&ring[sA0][l15 * 24 + i0a]);
    s16x8 a1 = *reinterpret_cast<const s16x8*>(&ring[sA1][l15 * 24 + i0a]);
    f32x4 sa = MFMA16(a1, cW2[1], MFMA16(a0, cW2[0], b2v4));
    short* sw = &s_s[buf][0];
    float m0 = sa[0] > 0.f ? sa[0] : 0.f;
    float m1 = sa[1] > 0.f ? sa[1] : 0.f;
    float m2 = sa[2] > 0.f ? sa[2] : 0.f;
    float m3 = sa[3] > 0.f ? sa[3] : 0.f;
    uint32_t u01, u23;
    asm("v_cvt_pk_bf16_f32 %0, %1, %2" : "=v"(u01) : "v"(m0), "v"(m1));
    asm("v_cvt_pk_bf16_f32 %0, %1, %2" : "=v"(u23) : "v"(m2), "v"(m3));
    const int cbase = (wv & 1) * 16 + l15;
    sw[(lg * 4 + 0) * 40 + cbase] = (short)(u01 & 0xffff);
    sw[(lg * 4 + 1) * 40 + cbase] = (short)(u01 >> 16);
    sw[(lg * 4 + 2) * 40 + cbase] = (short)(u23 & 0xffff);
    sw[(lg * 4 + 3) * 40 + cbase] = (short)(u23 >> 16);
  };

  // ---- prologue: c1(0) -> s(0) -> c1(1) ----
  {
    float c = b1v + w1v2 * xa_r;              // c1(0): taps x(-2)=x(-1)=0
    c = c > 0.f ? c : 0.f;
    ring[0][sl * 24 + chc] = f2bf(c);
  }
  __syncthreads();
  if (wv < 2) conv2_step(0, 0);               // s(0); slots 1..3 are zero
  {
    float c = b1v + w1v1 * xa_r + w1v2 * xb_r; // c1(1)
    c = c > 0.f ? c : 0.f;
    ring[1][sl * 24 + chc] = f2bf(c);
  }
  __syncthreads();

  float hreg[4] = {0.f, 0.f, 0.f, 0.f};

  for (int t = 0; t < T; ++t) {
    // A-fragments: s(t) and h(t-1)
    s16x8 as_ = *reinterpret_cast<const s16x8*>(&s_s[t & 1][l15 * 40 + lg * 8]);
    const short* hb = &hA[t & 1][0];
    const int ho = l15 * 72 + lg * 8;
    s16x8 ah0 = *reinterpret_cast<const s16x8*>(hb + ho);
    s16x8 ah1 = *reinterpret_cast<const s16x8*>(hb + ho + 32);

    // r/z: fully-fused 5-deep chains (xp + gh + both biases, zero VALU adds)
    f32x4 pre_r = MFMA16(as_, WihHi[0],
                  MFMA16(ah1, WhhLo[0][1],
                  MFMA16(ah0, WhhLo[0][0],
                  MFMA16(ah1, WhhHi[0][1],
                  MFMA16(ah0, WhhHi[0][0], bias_r)))));
    f32x4 pre_z = MFMA16(as_, WihHi[1],
                  MFMA16(ah1, WhhLo[1][1],
                  MFMA16(ah0, WhhLo[1][0],
                  MFMA16(ah1, WhhHi[1][1],
                  MFMA16(ah0, WhhHi[1][0], bias_z)))));
    // n: xn and hn kept separate (r multiplies hn only)
    f32x4 xn = MFMA16(as_, WihHi[2], bias_xn);
    f32x4 hn = MFMA16(ah1, WhhLo[2][1],
               MFMA16(ah0, WhhLo[2][0],
               MFMA16(ah1, WhhHi[2][1],
               MFMA16(ah0, WhhHi[2][0], bias_hn))));

    // pipeline: produce s(t+1) and c1(t+2) for later steps
    if (t < T - 1 && wv < 2) conv2_step(t + 1, (t + 1) & 1);

    if (t < T - 2) {
      float xc = x_s[sl * T + t + 2];
      float c = b1v + w1v0 * xa_r + w1v1 * xb_r + w1v2 * xc;  // c1(t+2)
      c = c > 0.f ? c : 0.f;
      ring[(t + 2) & 3][sl * 24 + chc] = f2bf(c);
      xa_r = xb_r; xb_r = xc;
    }

    // GRU elementwise; D layout: seq = lg*4+i2, hidden dim j = 16*wv + l15
    float hnew[4];
#pragma unroll
    for (int i2 = 0; i2 < 4; ++i2) {
      float r = sigm_fast(pre_r[i2]);
      float z = sigm_fast(pre_z[i2]);
      float arg = __builtin_fmaf(r, hn[i2], xn[i2]);
      float tn = tanh_fast(arg);
      float h = __builtin_fmaf(z, hreg[i2] - tn, tn);  // (1-z)n + z h
      hreg[i2] = h;
      hnew[i2] = h;
    }
    short* hw = &hA[(t + 1) & 1][0];
    uint32_t p01, p23;
    asm("v_cvt_pk_bf16_f32 %0, %1, %2" : "=v"(p01) : "v"(hnew[0]), "v"(hnew[1]));
    asm("v_cvt_pk_bf16_f32 %0, %1, %2" : "=v"(p23) : "v"(hnew[2]), "v"(hnew[3]));
    const int hbase = 16 * wv + l15;
    hw[(lg * 4 + 0) * 72 + hbase] = (short)(p01 & 0xffff);
    hw[(lg * 4 + 1) * 72 + hbase] = (short)(p01 >> 16);
    hw[(lg * 4 + 2) * 72 + hbase] = (short)(p23 & 0xffff);
    hw[(lg * 4 + 3) * 72 + hbase] = (short)(p23 >> 16);
    __syncthreads();
  }

#pragma unroll
  for (int i2 = 0; i2 < 4; ++i2) {
    out[(size_t)(seq0 + lg * 4 + i2) * 64 + 16 * wv + l15] = hreg[i2];
  }
}

extern "C" void kernel_launch(void* const* d_in, const int* in_sizes, int n_in,
                              void* d_out, int out_size, void* d_ws, size_t ws_size,
                              hipStream_t stream)
{
  (void)in_sizes; (void)n_in; (void)d_ws; (void)ws_size; (void)out_size;
  const float* x   = (const float*)d_in[0];
  const float* w1  = (const float*)d_in[1];
  const float* b1  = (const float*)d_in[2];
  const float* w2  = (const float*)d_in[3];
  const float* b2  = (const float*)d_in[4];
  const float* Wih = (const float*)d_in[5];
  const float* Whh = (const float*)d_in[6];
  const float* bih = (const float*)d_in[7];
  const float* bhh = (const float*)d_in[8];
  float* out = (float*)d_out;
  te_fused<<<512, 256, 0, stream>>>(x, w1, b1, w2, b2, Wih, Whh, bih, bhh, out);
}

// Round 5
// 79.827 us; speedup vs baseline: 9.3723x; 1.1111x over previous
//
#include <hip/hip_runtime.h>
#include <stdint.h>

typedef __attribute__((ext_vector_type(8))) short s16x8;
typedef __attribute__((ext_vector_type(4))) float f32x4;

__device__ __forceinline__ short f2bf(float f){
  union { float f; uint32_t u; } v; v.f = f;
  uint32_t u = v.u;
  u += 0x7fffu + ((u >> 16) & 1u);
  return (short)(u >> 16);
}
__device__ __forceinline__ float sigm_fast(float x){
  float e = __builtin_amdgcn_exp2f(x * -1.44269504f);
  return __builtin_amdgcn_rcpf(1.f + e);
}
__device__ __forceinline__ float tanh_fast(float x){
  float e = __builtin_amdgcn_exp2f(x * 2.88539008f);
  return __builtin_fmaf(-2.f, __builtin_amdgcn_rcpf(e + 1.f), 1.f);
}

#define MFMA16(a, b, c) __builtin_amdgcn_mfma_f32_16x16x32_bf16((a), (b), (c), 0, 0, 0)

// Fused TemporalEncoder: conv1(1->16,k3,causal)+ReLU -> conv2(16->32,k3,causal)+ReLU
// -> GRU(32->64) over T=100, emit final hidden state.
// Block = 256 threads (4 waves) owns M=16 sequences; grid = 512 (2 blocks/CU).
// Round-4 lesson: absmax pinned at 2^-9 across precision configs -> Whh split-2
// compensation buys nothing measurable; dropped (16->9 MFMA/wave/step, chains
// 5->3 deep, -24 VGPR). M=8-for-TLP rejected: elementwise VALU (24 quarter-rate
// transcendentals/wave/step) is wave-wide -> M=8 doubles per-CU VALU issue.
__global__ __launch_bounds__(256, 2) void te_fused(
    const float* __restrict__ x,
    const float* __restrict__ w1, const float* __restrict__ b1,
    const float* __restrict__ w2, const float* __restrict__ b2,
    const float* __restrict__ Wih, const float* __restrict__ Whh,
    const float* __restrict__ bih, const float* __restrict__ bhh,
    float* __restrict__ out)
{
  constexpr int T = 100;
  constexpr int M = 16;                  // sequences per block (full MFMA tiles)
  __shared__ float x_s[M * T];           // staged input rows
  __shared__ short hA[2][16 * 72];       // [buf][seq][72-padded dim] bf16 h
  __shared__ short ring[4][16 * 24];     // c1 ring: [slot=tau%4][seq][24-padded ch(16)]
  __shared__ short s_s[2][16 * 40];      // conv2 out s_t: [buf][seq][40-padded ch(32)]

  const int tid  = threadIdx.x;
  const int lane = tid & 63;
  const int wv   = tid >> 6;    // wave 0..3
  const int l15  = lane & 15;
  const int lg   = lane >> 4;   // 0..3
  const int seq0 = blockIdx.x * M;
  const int sl   = tid >> 4;    // conv1: seq row 0..15
  const int chc  = tid & 15;    // conv1: channel 0..15

  // ---- stage x (16*100 floats per block, 16B aligned) ----
  {
    const float4* gx = reinterpret_cast<const float4*>(x + (size_t)seq0 * T);
    float4* sx = reinterpret_cast<float4*>(x_s);
    for (int i = tid; i < (M * T) / 4; i += 256) sx[i] = gx[i];
  }
  // zero h buffer 0 and the whole c1 ring (prologue + stale slots must be 0/finite)
  {
    int* p = reinterpret_cast<int*>(&hA[0][0]);
    for (int i = tid; i < (16 * 72) / 2; i += 256) p[i] = 0;
    int* q = reinterpret_cast<int*>(&ring[0][0]);
    for (int i = tid; i < (4 * 16 * 24) / 2; i += 256) q[i] = 0;
  }

  // ---- weight B-fragments in registers ----
  // B[k][n]: lane holds n = l15 (+tile base), k = lg*8 + j (+32*ks)
  s16x8 WhhHi[3][2], WihHi[3];
  f32x4 bias_r, bias_z, bias_xn, bias_hn;
#pragma unroll
  for (int g = 0; g < 3; ++g) {
    const int n = 64 * g + 16 * wv + l15;      // global gate row
#pragma unroll
    for (int ks = 0; ks < 2; ++ks) {
      const float* p = Whh + n * 64 + ks * 32 + lg * 8;
#pragma unroll
      for (int j = 0; j < 8; ++j) WhhHi[g][ks][j] = f2bf(p[j]);
    }
    const float* q = Wih + n * 32 + lg * 8;
#pragma unroll
    for (int j = 0; j < 8; ++j) WihHi[g][j] = f2bf(q[j]);
    float bi = bih[n], bh = bhh[n];
    if (g == 0) { float v = bi + bh; bias_r  = (f32x4){v, v, v, v}; }
    if (g == 1) { float v = bi + bh; bias_z  = (f32x4){v, v, v, v}; }
    if (g == 2) { bias_xn = (f32x4){bi, bi, bi, bi};
                  bias_hn = (f32x4){bh, bh, bh, bh}; }
  }

  // conv2 B-fragments, FIXED tap mapping (slot rotation moved to A addresses):
  // flat k = ks*32 + lg*8 + j; group g = k>>4 (0..3); g<3 -> tap g, g==3 -> 0.
  s16x8 cW2[2];
  f32x4 b2v4;
  {
    const int nt = wv & 1;
    const int ch = 16 * nt + l15;
    float bv = b2[ch];
    b2v4 = (f32x4){bv, bv, bv, bv};
#pragma unroll
    for (int ks = 0; ks < 2; ++ks) {
      s16x8 h8;
#pragma unroll
      for (int j = 0; j < 8; ++j) {
        const int k = ks * 32 + lg * 8 + j;
        const int g = k >> 4, ii = k & 15;
        h8[j] = (g < 3) ? f2bf(w2[ch * 48 + ii * 3 + g]) : (short)0;
      }
      cW2[ks] = h8;
    }
  }

  // conv1 per-thread weights
  const float w1v0 = w1[chc * 3 + 0], w1v1 = w1[chc * 3 + 1], w1v2 = w1[chc * 3 + 2];
  const float b1v = b1[chc];

  __syncthreads();

  float xa_r = x_s[sl * T + 0];
  float xb_r = x_s[sl * T + 1];

  // conv2 A addressing: frag0 covers k-groups {0,1} (tap u-2+g), frag1 groups {2,3}.
  // slot(tap g) = (u-2+g) & 3. Group 3 is multiplied by B=0 (reads stale-but-
  // finite slot; ring only ever holds ReLU'd bf16 or 0 -> no NaN).
  const int i0a = (lg & 1) * 8;
  const int grp = lg >> 1;

  auto conv2_step = [&](int u, int buf) {
    const int sA0 = (u + 2 + grp) & 3;
    const int sA1 = (u + grp) & 3;
    s16x8 a0 = *reinterpret_cast<const s16x8*>(&ring[sA0][l15 * 24 + i0a]);
    s16x8 a1 = *reinterpret_cast<const s16x8*>(&ring[sA1][l15 * 24 + i0a]);
    f32x4 sa = MFMA16(a1, cW2[1], MFMA16(a0, cW2[0], b2v4));
    short* sw = &s_s[buf][0];
    float m0 = sa[0] > 0.f ? sa[0] : 0.f;
    float m1 = sa[1] > 0.f ? sa[1] : 0.f;
    float m2 = sa[2] > 0.f ? sa[2] : 0.f;
    float m3 = sa[3] > 0.f ? sa[3] : 0.f;
    uint32_t u01, u23;
    asm("v_cvt_pk_bf16_f32 %0, %1, %2" : "=v"(u01) : "v"(m0), "v"(m1));
    asm("v_cvt_pk_bf16_f32 %0, %1, %2" : "=v"(u23) : "v"(m2), "v"(m3));
    const int cbase = (wv & 1) * 16 + l15;
    sw[(lg * 4 + 0) * 40 + cbase] = (short)(u01 & 0xffff);
    sw[(lg * 4 + 1) * 40 + cbase] = (short)(u01 >> 16);
    sw[(lg * 4 + 2) * 40 + cbase] = (short)(u23 & 0xffff);
    sw[(lg * 4 + 3) * 40 + cbase] = (short)(u23 >> 16);
  };

  // ---- prologue: c1(0) -> s(0) -> c1(1) ----
  {
    float c = b1v + w1v2 * xa_r;              // c1(0): taps x(-2)=x(-1)=0
    c = c > 0.f ? c : 0.f;
    uint32_t cu;
    asm("v_cvt_pk_bf16_f32 %0, %1, %2" : "=v"(cu) : "v"(c), "v"(c));
    ring[0][sl * 24 + chc] = (short)(cu & 0xffff);
  }
  __syncthreads();
  if (wv < 2) conv2_step(0, 0);               // s(0); slots 1..3 are zero
  {
    float c = b1v + w1v1 * xa_r + w1v2 * xb_r; // c1(1)
    c = c > 0.f ? c : 0.f;
    uint32_t cu;
    asm("v_cvt_pk_bf16_f32 %0, %1, %2" : "=v"(cu) : "v"(c), "v"(c));
    ring[1][sl * 24 + chc] = (short)(cu & 0xffff);
  }
  __syncthreads();

  float hreg[4] = {0.f, 0.f, 0.f, 0.f};

  for (int t = 0; t < T; ++t) {
    // A-fragments: s(t) and h(t-1)
    s16x8 as_ = *reinterpret_cast<const s16x8*>(&s_s[t & 1][l15 * 40 + lg * 8]);
    const short* hb = &hA[t & 1][0];
    const int ho = l15 * 72 + lg * 8;
    s16x8 ah0 = *reinterpret_cast<const s16x8*>(hb + ho);
    s16x8 ah1 = *reinterpret_cast<const s16x8*>(hb + ho + 32);

    // r/z: fused 3-deep chains (xp + gh + both biases, zero VALU adds)
    f32x4 pre_r = MFMA16(as_, WihHi[0],
                  MFMA16(ah1, WhhHi[0][1],
                  MFMA16(ah0, WhhHi[0][0], bias_r)));
    f32x4 pre_z = MFMA16(as_, WihHi[1],
                  MFMA16(ah1, WhhHi[1][1],
                  MFMA16(ah0, WhhHi[1][0], bias_z)));
    // n: xn and hn kept separate (r multiplies hn only)
    f32x4 xn = MFMA16(as_, WihHi[2], bias_xn);
    f32x4 hn = MFMA16(ah1, WhhHi[2][1],
               MFMA16(ah0, WhhHi[2][0], bias_hn));

    // pipeline: produce s(t+1) and c1(t+2) for later steps
    if (t < T - 1 && wv < 2) conv2_step(t + 1, (t + 1) & 1);

    if (t < T - 2) {
      float xc = x_s[sl * T + t + 2];
      float c = b1v + w1v0 * xa_r + w1v1 * xb_r + w1v2 * xc;  // c1(t+2)
      c = c > 0.f ? c : 0.f;
      uint32_t cu;
      asm("v_cvt_pk_bf16_f32 %0, %1, %2" : "=v"(cu) : "v"(c), "v"(c));
      ring[(t + 2) & 3][sl * 24 + chc] = (short)(cu & 0xffff);
      xa_r = xb_r; xb_r = xc;
    }

    // GRU elementwise; D layout: seq = lg*4+i2, hidden dim j = 16*wv + l15
    float hnew[4];
#pragma unroll
    for (int i2 = 0; i2 < 4; ++i2) {
      float r = sigm_fast(pre_r[i2]);
      float z = sigm_fast(pre_z[i2]);
      float arg = __builtin_fmaf(r, hn[i2], xn[i2]);
      float tn = tanh_fast(arg);
      float h = __builtin_fmaf(z, hreg[i2] - tn, tn);  // (1-z)n + z h
      hreg[i2] = h;
      hnew[i2] = h;
    }
    short* hw = &hA[(t + 1) & 1][0];
    uint32_t p01, p23;
    asm("v_cvt_pk_bf16_f32 %0, %1, %2" : "=v"(p01) : "v"(hnew[0]), "v"(hnew[1]));
    asm("v_cvt_pk_bf16_f32 %0, %1, %2" : "=v"(p23) : "v"(hnew[2]), "v"(hnew[3]));
    const int hbase = 16 * wv + l15;
    hw[(lg * 4 + 0) * 72 + hbase] = (short)(p01 & 0xffff);
    hw[(lg * 4 + 1) * 72 + hbase] = (short)(p01 >> 16);
    hw[(lg * 4 + 2) * 72 + hbase] = (short)(p23 & 0xffff);
    hw[(lg * 4 + 3) * 72 + hbase] = (short)(p23 >> 16);
    __syncthreads();
  }

#pragma unroll
  for (int i2 = 0; i2 < 4; ++i2) {
    out[(size_t)(seq0 + lg * 4 + i2) * 64 + 16 * wv + l15] = hreg[i2];
  }
}

extern "C" void kernel_launch(void* const* d_in, const int* in_sizes, int n_in,
                              void* d_out, int out_size, void* d_ws, size_t ws_size,
                              hipStream_t stream)
{
  (void)in_sizes; (void)n_in; (void)d_ws; (void)ws_size; (void)out_size;
  const float* x   = (const float*)d_in[0];
  const float* w1  = (const float*)d_in[1];
  const float* b1  = (const float*)d_in[2];
  const float* w2  = (const float*)d_in[3];
  const float* b2  = (const float*)d_in[4];
  const float* Wih = (const float*)d_in[5];
  const float* Whh = (const float*)d_in[6];
  const float* bih = (const float*)d_in[7];
  const float* bhh = (const float*)d_in[8];
  float* out = (float*)d_out;
  te_fused<<<512, 256, 0, stream>>>(x, w1, b1, w2, b2, Wih, Whh, bih, bhh, out);
}

// Round 6
// 74.110 us; speedup vs baseline: 10.0953x; 1.0771x over previous
//
#include <hip/hip_runtime.h>
#include <stdint.h>

typedef __attribute__((ext_vector_type(8))) short s16x8;
typedef __attribute__((ext_vector_type(4))) float f32x4;

__device__ __forceinline__ short f2bf(float f){
  union { float f; uint32_t u; } v; v.f = f;
  uint32_t u = v.u;
  u += 0x7fffu + ((u >> 16) & 1u);
  return (short)(u >> 16);
}
__device__ __forceinline__ float sigm_fast(float x){
  float e = __builtin_amdgcn_exp2f(x * -1.44269504f);
  return __builtin_amdgcn_rcpf(1.f + e);
}
__device__ __forceinline__ float tanh_fast(float x){
  float e = __builtin_amdgcn_exp2f(x * 2.88539008f);
  return __builtin_fmaf(-2.f, __builtin_amdgcn_rcpf(e + 1.f), 1.f);
}

#define MFMA16(a, b, c) __builtin_amdgcn_mfma_f32_16x16x32_bf16((a), (b), (c), 0, 0, 0)

// Fused TemporalEncoder: conv1(1->16,k3)+ReLU -> conv2(16->32,k3)+ReLU -> GRU(32->64),
// T=100, emit final h. Block=256 threads (4 waves), M=16 seqs, grid=512 (2 blocks/CU).
// Round-6: phase-unroll x4 (all LDS addressing hoisted to base ptrs + compile-time
// phase offsets), conv1 moved to waves 2-3 (conv2 on 0-1) for barrier balance,
// setprio(1) around the gate-MFMA cluster (2 independent blocks/CU -> phase diversity).
__global__ __launch_bounds__(256, 2) void te_fused(
    const float* __restrict__ x,
    const float* __restrict__ w1, const float* __restrict__ b1,
    const float* __restrict__ w2, const float* __restrict__ b2,
    const float* __restrict__ Wih, const float* __restrict__ Whh,
    const float* __restrict__ bih, const float* __restrict__ bhh,
    float* __restrict__ out)
{
  constexpr int T = 100;
  constexpr int M = 16;
  __shared__ float x_s[M * T];           // staged input rows
  __shared__ short hA[2][16 * 72];       // [buf][seq][72-padded dim] bf16 h
  __shared__ short ring[4][16 * 24];     // c1 ring: [slot=tau%4][seq][24-padded ch]
  __shared__ short s_s[2][16 * 40];      // conv2 out: [buf][seq][40-padded ch(32)]

  const int tid  = threadIdx.x;
  const int lane = tid & 63;
  const int wv   = tid >> 6;
  const int l15  = lane & 15;
  const int lg   = lane >> 4;
  const int seq0 = blockIdx.x * M;

  // ---- stage x ----
  {
    const float4* gx = reinterpret_cast<const float4*>(x + (size_t)seq0 * T);
    float4* sx = reinterpret_cast<float4*>(x_s);
    for (int i = tid; i < (M * T) / 4; i += 256) sx[i] = gx[i];
  }
  // zero h buf0 and the whole ring
  {
    int* p = reinterpret_cast<int*>(&hA[0][0]);
    for (int i = tid; i < (16 * 72) / 2; i += 256) p[i] = 0;
    int* q = reinterpret_cast<int*>(&ring[0][0]);
    for (int i = tid; i < (4 * 16 * 24) / 2; i += 256) q[i] = 0;
  }

  // ---- weight B-fragments ----
  s16x8 WhhHi[3][2], WihHi[3];
  f32x4 bias_r, bias_z, bias_xn, bias_hn;
#pragma unroll
  for (int g = 0; g < 3; ++g) {
    const int n = 64 * g + 16 * wv + l15;
#pragma unroll
    for (int ks = 0; ks < 2; ++ks) {
      const float* p = Whh + n * 64 + ks * 32 + lg * 8;
#pragma unroll
      for (int j = 0; j < 8; ++j) WhhHi[g][ks][j] = f2bf(p[j]);
    }
    const float* q = Wih + n * 32 + lg * 8;
#pragma unroll
    for (int j = 0; j < 8; ++j) WihHi[g][j] = f2bf(q[j]);
    float bi = bih[n], bh = bhh[n];
    if (g == 0) { float v = bi + bh; bias_r  = (f32x4){v, v, v, v}; }
    if (g == 1) { float v = bi + bh; bias_z  = (f32x4){v, v, v, v}; }
    if (g == 2) { bias_xn = (f32x4){bi, bi, bi, bi};
                  bias_hn = (f32x4){bh, bh, bh, bh}; }
  }

  // conv2 B-frags: flat k group g = k>>4; g<3 -> tap g, g==3 -> 0 weight.
  s16x8 cW2[2];
  f32x4 b2v4;
  {
    const int ch = 16 * (wv & 1) + l15;
    float bv = b2[ch];
    b2v4 = (f32x4){bv, bv, bv, bv};
#pragma unroll
    for (int ks = 0; ks < 2; ++ks) {
      s16x8 h8;
#pragma unroll
      for (int j = 0; j < 8; ++j) {
        const int k = ks * 32 + lg * 8 + j;
        const int g = k >> 4, ii = k & 15;
        h8[j] = (g < 3) ? f2bf(w2[ch * 48 + ii * 3 + g]) : (short)0;
      }
      cW2[ks] = h8;
    }
  }

  // conv1 (waves 2-3): 2 (seq,ch) pairs per thread: seqs csl, csl+8
  const int cidx = tid & 127;
  const int csl  = cidx >> 4;       // 0..7
  const int cch  = cidx & 15;
  const float w1v0 = w1[cch * 3 + 0], w1v1 = w1[cch * 3 + 1], w1v2 = w1[cch * 3 + 2];
  const float b1v = b1[cch];

  // ---- hoisted LDS base pointers / per-phase offsets (shorts) ----
  const int i0a = (lg & 1) * 8;
  const int grp = lg >> 1;
  const short* ringRdBase = &ring[0][0] + l15 * 24 + i0a;
  int sA0off[4], sA1off[4];
#pragma unroll
  for (int p = 0; p < 4; ++p) {
    sA0off[p] = ((p + 3 + grp) & 3) * 384;   // conv2 frag0 slots (taps t-1, t)
    sA1off[p] = ((p + 1 + grp) & 3) * 384;   // conv2 frag1 slots (tap t+1, x0 grp)
  }
  const short* sRdBase = &s_s[0][0] + l15 * 40 + lg * 8;
  const short* hRdBase = &hA[0][0] + l15 * 72 + lg * 8;
  short* hWrBase = &hA[0][0] + (lg * 4) * 72 + 16 * wv + l15;
  short* swWr    = &s_s[0][0] + (lg * 4) * 40 + (wv & 1) * 16 + l15;
  short* ringWrA = &ring[0][0] + csl * 24 + cch;
  short* ringWrB = &ring[0][0] + (csl + 8) * 24 + cch;
  const float* xpA = &x_s[csl * T];
  const float* xpB = &x_s[(csl + 8) * T];

  __syncthreads();

#define CONV2_STEP(P_, WB_) do {                                              \
    s16x8 a0 = *reinterpret_cast<const s16x8*>(ringRdBase + sA0off[(P_)]);    \
    s16x8 a1 = *reinterpret_cast<const s16x8*>(ringRdBase + sA1off[(P_)]);    \
    f32x4 sa = MFMA16(a1, cW2[1], MFMA16(a0, cW2[0], b2v4));                  \
    float m0 = sa[0] > 0.f ? sa[0] : 0.f;                                     \
    float m1 = sa[1] > 0.f ? sa[1] : 0.f;                                     \
    float m2 = sa[2] > 0.f ? sa[2] : 0.f;                                     \
    float m3 = sa[3] > 0.f ? sa[3] : 0.f;                                     \
    uint32_t u01, u23;                                                        \
    asm("v_cvt_pk_bf16_f32 %0, %1, %2" : "=v"(u01) : "v"(m0), "v"(m1));       \
    asm("v_cvt_pk_bf16_f32 %0, %1, %2" : "=v"(u23) : "v"(m2), "v"(m3));       \
    swWr[(WB_) * 640 +   0] = (short)(u01 & 0xffff);                          \
    swWr[(WB_) * 640 +  40] = (short)(u01 >> 16);                             \
    swWr[(WB_) * 640 +  80] = (short)(u23 & 0xffff);                          \
    swWr[(WB_) * 640 + 120] = (short)(u23 >> 16);                             \
  } while (0)

  // ---- prologue: c1(0) -> sync -> s(0) & c1(1) -> sync ----
  float xaA = 0.f, xbA = 0.f, xaB = 0.f, xbB = 0.f;
  if (wv >= 2) {
    xaA = xpA[0]; xbA = xpA[1];
    xaB = xpB[0]; xbB = xpB[1];
    float cA = b1v + w1v2 * xaA; cA = cA > 0.f ? cA : 0.f;
    float cB = b1v + w1v2 * xaB; cB = cB > 0.f ? cB : 0.f;
    uint32_t cu;
    asm("v_cvt_pk_bf16_f32 %0, %1, %2" : "=v"(cu) : "v"(cA), "v"(cB));
    ringWrA[0] = (short)(cu & 0xffff);
    ringWrB[0] = (short)(cu >> 16);
  }
  __syncthreads();
  if (wv < 2) CONV2_STEP(3, 0);   // u=0 -> phase-3 slot pattern, write buf0
  if (wv >= 2) {
    float cA = b1v + w1v1 * xaA + w1v2 * xbA; cA = cA > 0.f ? cA : 0.f;
    float cB = b1v + w1v1 * xaB + w1v2 * xbB; cB = cB > 0.f ? cB : 0.f;
    uint32_t cu;
    asm("v_cvt_pk_bf16_f32 %0, %1, %2" : "=v"(cu) : "v"(cA), "v"(cB));
    ringWrA[384] = (short)(cu & 0xffff);
    ringWrB[384] = (short)(cu >> 16);
  }
  __syncthreads();

  float hreg[4] = {0.f, 0.f, 0.f, 0.f};

#define GRU_STEP(T_, P_, C2_, C1_) do {                                       \
    const int rb_ = (P_) & 1, wb_ = rb_ ^ 1;                                  \
    s16x8 as_ = *reinterpret_cast<const s16x8*>(sRdBase + rb_ * 640);         \
    s16x8 ah0 = *reinterpret_cast<const s16x8*>(hRdBase + rb_ * 1152);        \
    s16x8 ah1 = *reinterpret_cast<const s16x8*>(hRdBase + rb_ * 1152 + 32);   \
    __builtin_amdgcn_s_setprio(1);                                            \
    f32x4 pre_r = MFMA16(as_, WihHi[0],                                       \
                  MFMA16(ah1, WhhHi[0][1],                                    \
                  MFMA16(ah0, WhhHi[0][0], bias_r)));                         \
    f32x4 pre_z = MFMA16(as_, WihHi[1],                                       \
                  MFMA16(ah1, WhhHi[1][1],                                    \
                  MFMA16(ah0, WhhHi[1][0], bias_z)));                         \
    f32x4 xn = MFMA16(as_, WihHi[2], bias_xn);                                \
    f32x4 hn = MFMA16(ah1, WhhHi[2][1],                                       \
               MFMA16(ah0, WhhHi[2][0], bias_hn));                            \
    __builtin_amdgcn_s_setprio(0);                                            \
    if ((C2_) && wv < 2) { CONV2_STEP((P_), wb_); }                           \
    if ((C1_) && wv >= 2) {                                                   \
      float xcA = xpA[(T_) + 2], xcB = xpB[(T_) + 2];                         \
      float cA = b1v + w1v0 * xaA + w1v1 * xbA + w1v2 * xcA;                  \
      cA = cA > 0.f ? cA : 0.f;                                               \
      float cB = b1v + w1v0 * xaB + w1v1 * xbB + w1v2 * xcB;                  \
      cB = cB > 0.f ? cB : 0.f;                                               \
      uint32_t cu_;                                                           \
      asm("v_cvt_pk_bf16_f32 %0, %1, %2" : "=v"(cu_) : "v"(cA), "v"(cB));     \
      ringWrA[(((P_) + 2) & 3) * 384] = (short)(cu_ & 0xffff);                \
      ringWrB[(((P_) + 2) & 3) * 384] = (short)(cu_ >> 16);                   \
      xaA = xbA; xbA = xcA; xaB = xbB; xbB = xcB;                             \
    }                                                                         \
    float hnew[4];                                                            \
    _Pragma("unroll")                                                         \
    for (int i2 = 0; i2 < 4; ++i2) {                                          \
      float r = sigm_fast(pre_r[i2]);                                         \
      float z = sigm_fast(pre_z[i2]);                                         \
      float arg = __builtin_fmaf(r, hn[i2], xn[i2]);                          \
      float tn = tanh_fast(arg);                                              \
      float h = __builtin_fmaf(z, hreg[i2] - tn, tn);                         \
      hreg[i2] = h;                                                           \
      hnew[i2] = h;                                                           \
    }                                                                         \
    uint32_t p01, p23;                                                        \
    asm("v_cvt_pk_bf16_f32 %0, %1, %2" : "=v"(p01) : "v"(hnew[0]), "v"(hnew[1])); \
    asm("v_cvt_pk_bf16_f32 %0, %1, %2" : "=v"(p23) : "v"(hnew[2]), "v"(hnew[3])); \
    hWrBase[wb_ * 1152 +   0] = (short)(p01 & 0xffff);                        \
    hWrBase[wb_ * 1152 +  72] = (short)(p01 >> 16);                           \
    hWrBase[wb_ * 1152 + 144] = (short)(p23 & 0xffff);                        \
    hWrBase[wb_ * 1152 + 216] = (short)(p23 >> 16);                           \
    __syncthreads();                                                          \
  } while (0)

#pragma unroll 1
  for (int t = 0; t < 96; t += 4) {
    GRU_STEP(t + 0, 0, true, true);
    GRU_STEP(t + 1, 1, true, true);
    GRU_STEP(t + 2, 2, true, true);
    GRU_STEP(t + 3, 3, true, true);
  }
  GRU_STEP(96, 0, true, true);
  GRU_STEP(97, 1, true, true);
  GRU_STEP(98, 2, true, false);
  GRU_STEP(99, 3, false, false);

#pragma unroll
  for (int i2 = 0; i2 < 4; ++i2) {
    out[(size_t)(seq0 + lg * 4 + i2) * 64 + 16 * wv + l15] = hreg[i2];
  }
}

extern "C" void kernel_launch(void* const* d_in, const int* in_sizes, int n_in,
                              void* d_out, int out_size, void* d_ws, size_t ws_size,
                              hipStream_t stream)
{
  (void)in_sizes; (void)n_in; (void)d_ws; (void)ws_size; (void)out_size;
  const float* x   = (const float*)d_in[0];
  const float* w1  = (const float*)d_in[1];
  const float* b1  = (const float*)d_in[2];
  const float* w2  = (const float*)d_in[3];
  const float* b2  = (const float*)d_in[4];
  const float* Wih = (const float*)d_in[5];
  const float* Whh = (const float*)d_in[6];
  const float* bih = (const float*)d_in[7];
  const float* bhh = (const float*)d_in[8];
  float* out = (float*)d_out;
  te_fused<<<512, 256, 0, stream>>>(x, w1, b1, w2, b2, Wih, Whh, bih, bhh, out);
}